// Round 1
// baseline (1690.561 us; speedup 1.0000x reference)
//
#include <hip/hip_runtime.h>
#include <hip/hip_bf16.h>

#define NN 50000
#define EE 800000
#define DD 128
#define HH 128
#define CC 16
#define GG 512

// ---------------- degree / norm ----------------
__global__ __launch_bounds__(256) void k_init_deg(float* deg) {
    int i = blockIdx.x * 256 + threadIdx.x;
    if (i < NN) deg[i] = 1.0f;  // self loop
}

__global__ __launch_bounds__(256) void k_accum_deg(const int* __restrict__ ei, float* deg) {
    int e = blockIdx.x * 256 + threadIdx.x;
    if (e < EE) atomicAdd(&deg[ei[EE + e]], 1.0f);  // dst = ei[1][e]
}

__global__ __launch_bounds__(256) void k_rsqrt(float* deg) {
    int i = blockIdx.x * 256 + threadIdx.x;
    if (i < NN) deg[i] = rsqrtf(deg[i]);  // deg >= 1 always
}

// ---------------- GEMM: Out[N,128] = X[N,128] @ W[128,128] ----------------
// 16 rows per block, 256 threads: thread = (colgroup of 4) x (2 rows)
__global__ __launch_bounds__(256) void k_gemm(const float* __restrict__ X,
                                              const float* __restrict__ W,
                                              float* __restrict__ Out) {
    __shared__ float Wlds[128 * 128];
    const float4* W4 = (const float4*)W;
    float4* Wl4 = (float4*)Wlds;
    #pragma unroll
    for (int idx = threadIdx.x; idx < 128 * 128 / 4; idx += 256) Wl4[idx] = W4[idx];
    __syncthreads();

    const int c4 = (threadIdx.x & 31) * 4;   // column base 0..124
    const int rg = threadIdx.x >> 5;         // 0..7
    const int row0 = blockIdx.x * 16 + rg * 2;
    const float* x0 = X + (size_t)row0 * 128;
    const float* x1 = x0 + 128;

    float acc0x = 0.f, acc0y = 0.f, acc0z = 0.f, acc0w = 0.f;
    float acc1x = 0.f, acc1y = 0.f, acc1z = 0.f, acc1w = 0.f;

    for (int kk = 0; kk < 128; kk += 8) {
        float4 a0 = *(const float4*)(x0 + kk);
        float4 a1 = *(const float4*)(x0 + kk + 4);
        float4 b0 = *(const float4*)(x1 + kk);
        float4 b1 = *(const float4*)(x1 + kk + 4);
        float xr0[8] = {a0.x, a0.y, a0.z, a0.w, a1.x, a1.y, a1.z, a1.w};
        float xr1[8] = {b0.x, b0.y, b0.z, b0.w, b1.x, b1.y, b1.z, b1.w};
        #pragma unroll
        for (int t = 0; t < 8; ++t) {
            float4 w = *(const float4*)(Wlds + (kk + t) * 128 + c4);
            acc0x += xr0[t] * w.x; acc0y += xr0[t] * w.y;
            acc0z += xr0[t] * w.z; acc0w += xr0[t] * w.w;
            acc1x += xr1[t] * w.x; acc1y += xr1[t] * w.y;
            acc1z += xr1[t] * w.z; acc1w += xr1[t] * w.w;
        }
    }
    *(float4*)(Out + (size_t)row0 * 128 + c4)       = make_float4(acc0x, acc0y, acc0z, acc0w);
    *(float4*)(Out + (size_t)(row0 + 1) * 128 + c4) = make_float4(acc1x, acc1y, acc1z, acc1w);
}

// ---------------- edge scatter: Out[dst] += H[src] * dis[src]*dis[dst] ----------------
// one wave (64 lanes) per edge, 2 features per lane
__global__ __launch_bounds__(256) void k_scatter(const float* __restrict__ Hsrc,
                                                 const int* __restrict__ ei,
                                                 const float* __restrict__ dis,
                                                 float* __restrict__ Out) {
    long long gid = (long long)blockIdx.x * 256 + threadIdx.x;
    int e = (int)(gid >> 6);
    int f = ((int)gid & 63) * 2;
    int s = ei[e];
    int d = ei[EE + e];
    float nrm = dis[s] * dis[d];
    float2 h = *(const float2*)(Hsrc + (size_t)s * 128 + f);
    float* o = Out + (size_t)d * 128 + f;
    atomicAdd(o,     h.x * nrm);
    atomicAdd(o + 1, h.y * nrm);
}

// ---------------- finalize: x = relu(acc + h*dis^2 + b), fused pooling ----------------
__global__ __launch_bounds__(256) void k_finalize(const float* __restrict__ Hbuf,
                                                  const float* __restrict__ dis,
                                                  const float* __restrict__ bias,
                                                  const int* __restrict__ batch,
                                                  float* __restrict__ Xout,
                                                  float* __restrict__ gsum,
                                                  float* __restrict__ gmax,
                                                  float* __restrict__ cnt,
                                                  int do_cnt) {
    int gid = blockIdx.x * 256 + threadIdx.x;
    int i = gid >> 7, f = gid & 127;
    float di = dis[i];
    float v = Xout[gid] + Hbuf[gid] * di * di + bias[f];
    v = fmaxf(v, 0.f);
    Xout[gid] = v;
    int b = batch[i];
    atomicAdd(&gsum[b * 128 + f], v);
    atomicMax((int*)&gmax[b * 128 + f], __float_as_int(v));  // v>=0 -> int order == float order
    if (f == 0 && do_cnt) atomicAdd(cnt + b, 1.0f);
}

// ---------------- final MLP: one block per graph ----------------
__global__ __launch_bounds__(256) void k_mlp(const float* __restrict__ gsum0,
                                             const float* __restrict__ gmax0,
                                             const float* __restrict__ gsum1,
                                             const float* __restrict__ gmax1,
                                             const float* __restrict__ cnt,
                                             const float* __restrict__ lW1,
                                             const float* __restrict__ lb1,
                                             const float* __restrict__ lW2,
                                             const float* __restrict__ lb2,
                                             float* __restrict__ out) {
    __shared__ float gl[512];
    __shared__ float hb[256];
    __shared__ float part[256];
    int r = blockIdx.x;
    float inv = 1.0f / fmaxf(cnt[r], 1.0f);
    for (int k = threadIdx.x; k < 512; k += 256) {
        int seg = k >> 7, f = k & 127;
        float v;
        if (seg == 0)      v = gsum0[r * 128 + f] * inv;
        else if (seg == 1) v = gmax0[r * 128 + f];
        else if (seg == 2) v = gsum1[r * 128 + f] * inv;
        else               v = gmax1[r * 128 + f];
        gl[k] = v;
    }
    __syncthreads();
    {
        int j = threadIdx.x;
        float acc = lb1[j];
        for (int k = 0; k < 512; ++k) acc += gl[k] * lW1[k * 256 + j];
        hb[j] = fmaxf(acc, 0.f);
    }
    __syncthreads();
    {
        int c = threadIdx.x & 15, ch = threadIdx.x >> 4;
        float p = 0.f;
        #pragma unroll
        for (int j2 = 0; j2 < 16; ++j2) p += hb[ch * 16 + j2] * lW2[(ch * 16 + j2) * 16 + c];
        part[threadIdx.x] = p;
    }
    __syncthreads();
    if (threadIdx.x < 16) {
        float s = lb2[threadIdx.x];
        #pragma unroll
        for (int ch2 = 0; ch2 < 16; ++ch2) s += part[ch2 * 16 + threadIdx.x];
        out[r * 16 + threadIdx.x] = s;
    }
}

extern "C" void kernel_launch(void* const* d_in, const int* in_sizes, int n_in,
                              void* d_out, int out_size, void* d_ws, size_t ws_size,
                              hipStream_t stream) {
    const float* x    = (const float*)d_in[0];
    const int*   ei   = (const int*)d_in[1];
    const int*   batch= (const int*)d_in[2];
    const float* W1   = (const float*)d_in[3];
    const float* b1   = (const float*)d_in[4];
    const float* W2   = (const float*)d_in[5];
    const float* b2   = (const float*)d_in[6];
    const float* lW1  = (const float*)d_in[7];
    const float* lb1  = (const float*)d_in[8];
    const float* lW2  = (const float*)d_in[9];
    const float* lb2  = (const float*)d_in[10];
    float* out = (float*)d_out;

    // workspace layout (floats)
    float* bufA  = (float*)d_ws;                       // N*H : h (then h2)
    float* bufB  = bufA + (size_t)NN * HH;             // N*H : x0 (then x1 accum)
    float* dis   = bufB + (size_t)NN * HH;             // N (deg -> dis in place)
    float* gsum0 = dis + 50176;                        // padded
    float* gmax0 = gsum0 + GG * HH;
    float* gsum1 = gmax0 + GG * HH;
    float* gmax1 = gsum1 + GG * HH;
    float* cnt   = gmax1 + GG * HH;                    // G

    // 1) degree / norm
    k_init_deg<<<(NN + 255) / 256, 256, 0, stream>>>(dis);
    k_accum_deg<<<(EE + 255) / 256, 256, 0, stream>>>(ei, dis);
    k_rsqrt<<<(NN + 255) / 256, 256, 0, stream>>>(dis);

    // zero pools (gsum0..cnt contiguous)
    hipMemsetAsync(gsum0, 0, (size_t)(4 * GG * HH + GG) * sizeof(float), stream);

    // 2) conv1
    k_gemm<<<NN / 16, 256, 0, stream>>>(x, W1, bufA);
    hipMemsetAsync(bufB, 0, (size_t)NN * HH * sizeof(float), stream);
    k_scatter<<<(int)(((long long)EE * 64) / 256), 256, 0, stream>>>(bufA, ei, dis, bufB);
    k_finalize<<<NN * HH / 256, 256, 0, stream>>>(bufA, dis, b1, batch, bufB, gsum0, gmax0, cnt, 1);

    // 3) conv2
    k_gemm<<<NN / 16, 256, 0, stream>>>(bufB, W2, bufA);
    hipMemsetAsync(bufB, 0, (size_t)NN * HH * sizeof(float), stream);
    k_scatter<<<(int)(((long long)EE * 64) / 256), 256, 0, stream>>>(bufA, ei, dis, bufB);
    k_finalize<<<NN * HH / 256, 256, 0, stream>>>(bufA, dis, b2, batch, bufB, gsum1, gmax1, cnt, 0);

    // 4) MLP head
    k_mlp<<<GG, 256, 0, stream>>>(gsum0, gmax0, gsum1, gmax1, cnt, lW1, lb1, lW2, lb2, out);
}

// Round 2
// 558.969 us; speedup vs baseline: 3.0244x; 3.0244x over previous
//
#include <hip/hip_runtime.h>
#include <hip/hip_bf16.h>

#define NN 50000
#define EE 800000
#define DD 128
#define HH 128
#define CC 16
#define GG 512
#define NBLK_SCAN 196   // ceil(50000/256)

// ---------------- degree (int, incoming edges only) ----------------
__global__ __launch_bounds__(256) void k_deg(const int* __restrict__ ei, int* __restrict__ deg) {
    int e = blockIdx.x * 256 + threadIdx.x;
    if (e < EE) atomicAdd(&deg[ei[EE + e]], 1);
}

__global__ __launch_bounds__(256) void k_dis(const int* __restrict__ deg, float* __restrict__ dis) {
    int i = blockIdx.x * 256 + threadIdx.x;
    if (i < NN) dis[i] = rsqrtf((float)deg[i] + 1.0f);  // +1 self loop
}

// ---------------- 2-level exclusive scan of deg -> row_start ----------------
__global__ __launch_bounds__(256) void k_scan1(const int* __restrict__ deg,
                                               int* __restrict__ offs, int* __restrict__ bsum) {
    __shared__ int tmp[256];
    int i = blockIdx.x * 256 + threadIdx.x;
    int v = (i < NN) ? deg[i] : 0;
    tmp[threadIdx.x] = v;
    __syncthreads();
    for (int off = 1; off < 256; off <<= 1) {
        int t = (threadIdx.x >= off) ? tmp[threadIdx.x - off] : 0;
        __syncthreads();
        tmp[threadIdx.x] += t;
        __syncthreads();
    }
    if (i < NN) offs[i] = tmp[threadIdx.x] - v;  // exclusive
    if (threadIdx.x == 255) bsum[blockIdx.x] = tmp[255];
}

__global__ __launch_bounds__(256) void k_scan2(int* __restrict__ bsum) {
    __shared__ int tmp[256];
    int v = (threadIdx.x < NBLK_SCAN) ? bsum[threadIdx.x] : 0;
    tmp[threadIdx.x] = v;
    __syncthreads();
    for (int off = 1; off < 256; off <<= 1) {
        int t = (threadIdx.x >= off) ? tmp[threadIdx.x - off] : 0;
        __syncthreads();
        tmp[threadIdx.x] += t;
        __syncthreads();
    }
    bsum[threadIdx.x] = tmp[threadIdx.x] - v;  // exclusive
}

__global__ __launch_bounds__(256) void k_scan3(int* __restrict__ offs, const int* __restrict__ bsum,
                                               int* __restrict__ cursor) {
    int i = blockIdx.x * 256 + threadIdx.x;
    if (i < NN) {
        int v = offs[i] + bsum[blockIdx.x];
        offs[i] = v;
        cursor[i] = v;
    }
}

// ---------------- CSR fill: slot per incoming edge ----------------
__global__ __launch_bounds__(256) void k_fill(const int* __restrict__ ei, const float* __restrict__ dis,
                                              int* __restrict__ cursor,
                                              int* __restrict__ adj_src, float* __restrict__ adj_nrm) {
    int e = blockIdx.x * 256 + threadIdx.x;
    if (e >= EE) return;
    int s = ei[e];
    int d = ei[EE + e];
    int pos = atomicAdd(&cursor[d], 1);
    adj_src[pos] = s;
    adj_nrm[pos] = dis[s] * dis[d];
}

// ---------------- GEMM: Out[N,128] = X[N,128] @ W[128,128] ----------------
__global__ __launch_bounds__(256) void k_gemm(const float* __restrict__ X,
                                              const float* __restrict__ W,
                                              float* __restrict__ Out) {
    __shared__ float Wlds[128 * 128];
    const float4* W4 = (const float4*)W;
    float4* Wl4 = (float4*)Wlds;
    #pragma unroll
    for (int idx = threadIdx.x; idx < 128 * 128 / 4; idx += 256) Wl4[idx] = W4[idx];
    __syncthreads();

    const int c4 = (threadIdx.x & 31) * 4;
    const int rg = threadIdx.x >> 5;
    const int row0 = blockIdx.x * 16 + rg * 2;
    const float* x0 = X + (size_t)row0 * 128;
    const float* x1 = x0 + 128;

    float acc0x = 0.f, acc0y = 0.f, acc0z = 0.f, acc0w = 0.f;
    float acc1x = 0.f, acc1y = 0.f, acc1z = 0.f, acc1w = 0.f;

    for (int kk = 0; kk < 128; kk += 8) {
        float4 a0 = *(const float4*)(x0 + kk);
        float4 a1 = *(const float4*)(x0 + kk + 4);
        float4 b0 = *(const float4*)(x1 + kk);
        float4 b1 = *(const float4*)(x1 + kk + 4);
        float xr0[8] = {a0.x, a0.y, a0.z, a0.w, a1.x, a1.y, a1.z, a1.w};
        float xr1[8] = {b0.x, b0.y, b0.z, b0.w, b1.x, b1.y, b1.z, b1.w};
        #pragma unroll
        for (int t = 0; t < 8; ++t) {
            float4 w = *(const float4*)(Wlds + (kk + t) * 128 + c4);
            acc0x += xr0[t] * w.x; acc0y += xr0[t] * w.y;
            acc0z += xr0[t] * w.z; acc0w += xr0[t] * w.w;
            acc1x += xr1[t] * w.x; acc1y += xr1[t] * w.y;
            acc1z += xr1[t] * w.z; acc1w += xr1[t] * w.w;
        }
    }
    *(float4*)(Out + (size_t)row0 * 128 + c4)       = make_float4(acc0x, acc0y, acc0z, acc0w);
    *(float4*)(Out + (size_t)(row0 + 1) * 128 + c4) = make_float4(acc1x, acc1y, acc1z, acc1w);
}

// ---------------- fused gather conv + self + bias + relu + pool ----------------
// one wave per dst node, 2 features per lane; 4 nodes per block
__global__ __launch_bounds__(256) void k_conv(const float* __restrict__ h,
                                              const int* __restrict__ adj_src,
                                              const float* __restrict__ adj_nrm,
                                              const int* __restrict__ row_start,
                                              const int* __restrict__ deg,
                                              const float* __restrict__ dis,
                                              const float* __restrict__ bias,
                                              const int* __restrict__ batch,
                                              float* __restrict__ xout,
                                              float* __restrict__ gsum,
                                              float* __restrict__ gmax,
                                              float* __restrict__ cnt,
                                              int flags) {  // 1 = write xout, 2 = count
    int node = blockIdx.x * 4 + (threadIdx.x >> 6);
    int lane = threadIdx.x & 63;
    int f = lane * 2;
    float di = dis[node];
    float2 hv = *(const float2*)(h + (size_t)node * 128 + f);
    float2 bv = *(const float2*)(bias + f);
    float accx = hv.x * di * di + bv.x;
    float accy = hv.y * di * di + bv.y;
    int rs = row_start[node];
    int n  = deg[node];
    for (int k = 0; k < n; ++k) {
        int s = adj_src[rs + k];
        float nrm = adj_nrm[rs + k];
        float2 v = *(const float2*)(h + (size_t)s * 128 + f);
        accx += v.x * nrm;
        accy += v.y * nrm;
    }
    accx = fmaxf(accx, 0.f);
    accy = fmaxf(accy, 0.f);
    if (flags & 1) *(float2*)(xout + (size_t)node * 128 + f) = make_float2(accx, accy);
    int b = batch[node];
    atomicAdd(&gsum[b * 128 + f],     accx);
    atomicAdd(&gsum[b * 128 + f + 1], accy);
    atomicMax((int*)&gmax[b * 128 + f],     __float_as_int(accx));  // v>=0
    atomicMax((int*)&gmax[b * 128 + f + 1], __float_as_int(accy));
    if (lane == 0 && (flags & 2)) atomicAdd(cnt + b, 1.0f);
}

// ---------------- final MLP: one block per graph ----------------
__global__ __launch_bounds__(256) void k_mlp(const float* __restrict__ gsum0,
                                             const float* __restrict__ gmax0,
                                             const float* __restrict__ gsum1,
                                             const float* __restrict__ gmax1,
                                             const float* __restrict__ cnt,
                                             const float* __restrict__ lW1,
                                             const float* __restrict__ lb1,
                                             const float* __restrict__ lW2,
                                             const float* __restrict__ lb2,
                                             float* __restrict__ out) {
    __shared__ float gl[512];
    __shared__ float hb[256];
    __shared__ float part[256];
    int r = blockIdx.x;
    float inv = 1.0f / fmaxf(cnt[r], 1.0f);
    for (int k = threadIdx.x; k < 512; k += 256) {
        int seg = k >> 7, f = k & 127;
        float v;
        if (seg == 0)      v = gsum0[r * 128 + f] * inv;
        else if (seg == 1) v = gmax0[r * 128 + f];
        else if (seg == 2) v = gsum1[r * 128 + f] * inv;
        else               v = gmax1[r * 128 + f];
        gl[k] = v;
    }
    __syncthreads();
    {
        int j = threadIdx.x;
        float acc = lb1[j];
        for (int k = 0; k < 512; ++k) acc += gl[k] * lW1[k * 256 + j];
        hb[j] = fmaxf(acc, 0.f);
    }
    __syncthreads();
    {
        int c = threadIdx.x & 15, ch = threadIdx.x >> 4;
        float p = 0.f;
        #pragma unroll
        for (int j2 = 0; j2 < 16; ++j2) p += hb[ch * 16 + j2] * lW2[(ch * 16 + j2) * 16 + c];
        part[threadIdx.x] = p;
    }
    __syncthreads();
    if (threadIdx.x < 16) {
        float s = lb2[threadIdx.x];
        #pragma unroll
        for (int ch2 = 0; ch2 < 16; ++ch2) s += part[ch2 * 16 + threadIdx.x];
        out[r * 16 + threadIdx.x] = s;
    }
}

extern "C" void kernel_launch(void* const* d_in, const int* in_sizes, int n_in,
                              void* d_out, int out_size, void* d_ws, size_t ws_size,
                              hipStream_t stream) {
    const float* x    = (const float*)d_in[0];
    const int*   ei   = (const int*)d_in[1];
    const int*   batch= (const int*)d_in[2];
    const float* W1   = (const float*)d_in[3];
    const float* b1   = (const float*)d_in[4];
    const float* W2   = (const float*)d_in[5];
    const float* b2   = (const float*)d_in[6];
    const float* lW1  = (const float*)d_in[7];
    const float* lb1  = (const float*)d_in[8];
    const float* lW2  = (const float*)d_in[9];
    const float* lb2  = (const float*)d_in[10];
    float* out = (float*)d_out;

    // workspace layout (4-byte units)
    float* bufA   = (float*)d_ws;                      // N*H : h
    float* bufB   = bufA + (size_t)NN * HH;            // N*H : x0
    float* dis    = bufB + (size_t)NN * HH;            // N (padded 50176)
    float* gsum0  = dis + 50176;
    float* gmax0  = gsum0 + GG * HH;
    float* gsum1  = gmax0 + GG * HH;
    float* gmax1  = gsum1 + GG * HH;
    float* cnt    = gmax1 + GG * HH;                   // G
    int*   deg    = (int*)(cnt + GG);                  // N (padded 50176)
    int*   offs   = deg + 50176;                       // N row_start
    int*   cursor = offs + 50176;                      // N
    int*   bsum   = cursor + 50176;                    // 256
    int*   adj_src= bsum + 256;                        // E
    float* adj_nrm= (float*)(adj_src + EE);            // E

    // ---- CSR build ----
    hipMemsetAsync(deg, 0, 50176 * sizeof(int), stream);
    k_deg<<<(EE + 255) / 256, 256, 0, stream>>>(ei, deg);
    k_dis<<<(NN + 255) / 256, 256, 0, stream>>>(deg, dis);
    k_scan1<<<NBLK_SCAN, 256, 0, stream>>>(deg, offs, bsum);
    k_scan2<<<1, 256, 0, stream>>>(bsum);
    k_scan3<<<NBLK_SCAN, 256, 0, stream>>>(offs, bsum, cursor);
    k_fill<<<(EE + 255) / 256, 256, 0, stream>>>(ei, dis, cursor, adj_src, adj_nrm);

    // ---- zero pool accumulators (contiguous) ----
    hipMemsetAsync(gsum0, 0, (size_t)(4 * GG * HH + GG) * sizeof(float), stream);

    // ---- conv1 ----
    k_gemm<<<NN / 16, 256, 0, stream>>>(x, W1, bufA);
    k_conv<<<NN / 4, 256, 0, stream>>>(bufA, adj_src, adj_nrm, offs, deg, dis, b1, batch,
                                       bufB, gsum0, gmax0, cnt, 3);
    // ---- conv2 ----
    k_gemm<<<NN / 16, 256, 0, stream>>>(bufB, W2, bufA);
    k_conv<<<NN / 4, 256, 0, stream>>>(bufA, adj_src, adj_nrm, offs, deg, dis, b2, batch,
                                       bufB, gsum1, gmax1, cnt, 0);

    // ---- MLP head ----
    k_mlp<<<GG, 256, 0, stream>>>(gsum0, gmax0, gsum1, gmax1, cnt, lW1, lb1, lW2, lb2, out);
}

// Round 3
// 367.990 us; speedup vs baseline: 4.5940x; 1.5190x over previous
//
#include <hip/hip_runtime.h>
#include <hip/hip_bf16.h>

#define NN 50000
#define EE 800000
#define DD 128
#define HH 128
#define CC 16
#define GG 512
#define NBLK_SCAN 196   // ceil(50000/256)

// ---------------- degree (int, incoming edges only) ----------------
__global__ __launch_bounds__(256) void k_deg(const int* __restrict__ ei, int* __restrict__ deg) {
    int e = blockIdx.x * 256 + threadIdx.x;
    if (e < EE) atomicAdd(&deg[ei[EE + e]], 1);
}

__global__ __launch_bounds__(256) void k_dis(const int* __restrict__ deg, float* __restrict__ dis) {
    int i = blockIdx.x * 256 + threadIdx.x;
    if (i < NN) dis[i] = rsqrtf((float)deg[i] + 1.0f);  // +1 self loop
}

// ---------------- 2-level exclusive scan of deg -> row_start ----------------
__global__ __launch_bounds__(256) void k_scan1(const int* __restrict__ deg,
                                               int* __restrict__ offs, int* __restrict__ bsum) {
    __shared__ int tmp[256];
    int i = blockIdx.x * 256 + threadIdx.x;
    int v = (i < NN) ? deg[i] : 0;
    tmp[threadIdx.x] = v;
    __syncthreads();
    for (int off = 1; off < 256; off <<= 1) {
        int t = (threadIdx.x >= off) ? tmp[threadIdx.x - off] : 0;
        __syncthreads();
        tmp[threadIdx.x] += t;
        __syncthreads();
    }
    if (i < NN) offs[i] = tmp[threadIdx.x] - v;  // exclusive
    if (threadIdx.x == 255) bsum[blockIdx.x] = tmp[255];
}

__global__ __launch_bounds__(256) void k_scan2(int* __restrict__ bsum) {
    __shared__ int tmp[256];
    int v = (threadIdx.x < NBLK_SCAN) ? bsum[threadIdx.x] : 0;
    tmp[threadIdx.x] = v;
    __syncthreads();
    for (int off = 1; off < 256; off <<= 1) {
        int t = (threadIdx.x >= off) ? tmp[threadIdx.x - off] : 0;
        __syncthreads();
        tmp[threadIdx.x] += t;
        __syncthreads();
    }
    bsum[threadIdx.x] = tmp[threadIdx.x] - v;  // exclusive
}

__global__ __launch_bounds__(256) void k_scan3(int* __restrict__ offs, const int* __restrict__ bsum,
                                               int* __restrict__ cursor) {
    int i = blockIdx.x * 256 + threadIdx.x;
    if (i < NN) {
        int v = offs[i] + bsum[blockIdx.x];
        offs[i] = v;
        cursor[i] = v;
    }
}

// ---------------- CSR fill: packed (src, norm) per incoming edge ----------------
__global__ __launch_bounds__(256) void k_fill(const int* __restrict__ ei, const float* __restrict__ dis,
                                              int* __restrict__ cursor, int2* __restrict__ adj) {
    int e = blockIdx.x * 256 + threadIdx.x;
    if (e >= EE) return;
    int s = ei[e];
    int d = ei[EE + e];
    int pos = atomicAdd(&cursor[d], 1);
    adj[pos] = make_int2(s, __float_as_int(dis[s] * dis[d]));
}

// ---------------- GEMM: Out[N,128] = X[N,128] @ W[128,128] ----------------
__global__ __launch_bounds__(256) void k_gemm(const float* __restrict__ X,
                                              const float* __restrict__ W,
                                              float* __restrict__ Out) {
    __shared__ float Wlds[128 * 128];
    const float4* W4 = (const float4*)W;
    float4* Wl4 = (float4*)Wlds;
    #pragma unroll
    for (int idx = threadIdx.x; idx < 128 * 128 / 4; idx += 256) Wl4[idx] = W4[idx];
    __syncthreads();

    const int c4 = (threadIdx.x & 31) * 4;
    const int rg = threadIdx.x >> 5;
    const int row0 = blockIdx.x * 16 + rg * 2;
    const float* x0 = X + (size_t)row0 * 128;
    const float* x1 = x0 + 128;

    float acc0x = 0.f, acc0y = 0.f, acc0z = 0.f, acc0w = 0.f;
    float acc1x = 0.f, acc1y = 0.f, acc1z = 0.f, acc1w = 0.f;

    for (int kk = 0; kk < 128; kk += 8) {
        float4 a0 = *(const float4*)(x0 + kk);
        float4 a1 = *(const float4*)(x0 + kk + 4);
        float4 b0 = *(const float4*)(x1 + kk);
        float4 b1 = *(const float4*)(x1 + kk + 4);
        float xr0[8] = {a0.x, a0.y, a0.z, a0.w, a1.x, a1.y, a1.z, a1.w};
        float xr1[8] = {b0.x, b0.y, b0.z, b0.w, b1.x, b1.y, b1.z, b1.w};
        #pragma unroll
        for (int t = 0; t < 8; ++t) {
            float4 w = *(const float4*)(Wlds + (kk + t) * 128 + c4);
            acc0x += xr0[t] * w.x; acc0y += xr0[t] * w.y;
            acc0z += xr0[t] * w.z; acc0w += xr0[t] * w.w;
            acc1x += xr1[t] * w.x; acc1y += xr1[t] * w.y;
            acc1z += xr1[t] * w.z; acc1w += xr1[t] * w.w;
        }
    }
    *(float4*)(Out + (size_t)row0 * 128 + c4)       = make_float4(acc0x, acc0y, acc0z, acc0w);
    *(float4*)(Out + (size_t)(row0 + 1) * 128 + c4) = make_float4(acc1x, acc1y, acc1z, acc1w);
}

// ---------------- fused gather conv + self + bias + relu + pool ----------------
// one wave per dst node, 2 features per lane; 4 nodes per block
// 8x unrolled edge loop for memory-level parallelism; masked tail (min-clamp + zero weight)
__global__ __launch_bounds__(256) void k_conv(const float* __restrict__ h,
                                              const int2* __restrict__ adj,
                                              const int* __restrict__ row_start,
                                              const int* __restrict__ deg,
                                              const float* __restrict__ dis,
                                              const float* __restrict__ bias,
                                              const int* __restrict__ batch,
                                              float* __restrict__ xout,
                                              float* __restrict__ gsum,
                                              float* __restrict__ gmax,
                                              float* __restrict__ cnt,
                                              int flags) {  // 1 = write xout, 2 = count
    __shared__ float lacc[4][128];
    __shared__ int lb[4];
    int wid = threadIdx.x >> 6;
    int lane = threadIdx.x & 63;
    int node = blockIdx.x * 4 + wid;
    int f = lane * 2;
    float di = dis[node];
    float2 hv = *(const float2*)(h + (size_t)node * 128 + f);
    float2 bv = *(const float2*)(bias + f);
    float accx = hv.x * di * di + bv.x;
    float accy = hv.y * di * di + bv.y;
    int rs = row_start[node];
    int n  = deg[node];
    const int2* ap = adj + rs;
    if (n > 0) {
        for (int k = 0; k < n; k += 8) {
            int2 pk[8];
            #pragma unroll
            for (int j = 0; j < 8; ++j) pk[j] = ap[min(k + j, n - 1)];
            #pragma unroll
            for (int j = 0; j < 8; ++j) {
                float2 v = *(const float2*)(h + (size_t)pk[j].x * 128 + f);
                float w = (k + j < n) ? __int_as_float(pk[j].y) : 0.f;
                accx += v.x * w;
                accy += v.y * w;
            }
        }
    }
    accx = fmaxf(accx, 0.f);
    accy = fmaxf(accy, 0.f);
    if (flags & 1) *(float2*)(xout + (size_t)node * 128 + f) = make_float2(accx, accy);

    // block-level pool pre-reduction (batch is sorted -> runs of equal group)
    lacc[wid][f]     = accx;
    lacc[wid][f + 1] = accy;
    if (lane == 0) lb[wid] = batch[node];
    __syncthreads();
    if (wid == 0) {
        float sx = lacc[0][f], sy = lacc[0][f + 1];
        float mx = sx, my = sy;
        int cur = lb[0], run = 1;
        #pragma unroll
        for (int w = 1; w < 4; ++w) {
            float ax = lacc[w][f], ay = lacc[w][f + 1];
            if (lb[w] == cur) {
                sx += ax; sy += ay;
                mx = fmaxf(mx, ax); my = fmaxf(my, ay);
                run++;
            } else {
                atomicAdd(&gsum[cur * 128 + f],     sx);
                atomicAdd(&gsum[cur * 128 + f + 1], sy);
                atomicMax((int*)&gmax[cur * 128 + f],     __float_as_int(mx));
                atomicMax((int*)&gmax[cur * 128 + f + 1], __float_as_int(my));
                if (lane == 0 && (flags & 2)) atomicAdd(cnt + cur, (float)run);
                sx = ax; sy = ay; mx = ax; my = ay; cur = lb[w]; run = 1;
            }
        }
        atomicAdd(&gsum[cur * 128 + f],     sx);
        atomicAdd(&gsum[cur * 128 + f + 1], sy);
        atomicMax((int*)&gmax[cur * 128 + f],     __float_as_int(mx));
        atomicMax((int*)&gmax[cur * 128 + f + 1], __float_as_int(my));
        if (lane == 0 && (flags & 2)) atomicAdd(cnt + cur, (float)run);
    }
}

// ---------------- final MLP: one block per graph ----------------
__global__ __launch_bounds__(256) void k_mlp(const float* __restrict__ gsum0,
                                             const float* __restrict__ gmax0,
                                             const float* __restrict__ gsum1,
                                             const float* __restrict__ gmax1,
                                             const float* __restrict__ cnt,
                                             const float* __restrict__ lW1,
                                             const float* __restrict__ lb1,
                                             const float* __restrict__ lW2,
                                             const float* __restrict__ lb2,
                                             float* __restrict__ out) {
    __shared__ float gl[512];
    __shared__ float hb[256];
    __shared__ float part[256];
    int r = blockIdx.x;
    float inv = 1.0f / fmaxf(cnt[r], 1.0f);
    for (int k = threadIdx.x; k < 512; k += 256) {
        int seg = k >> 7, f = k & 127;
        float v;
        if (seg == 0)      v = gsum0[r * 128 + f] * inv;
        else if (seg == 1) v = gmax0[r * 128 + f];
        else if (seg == 2) v = gsum1[r * 128 + f] * inv;
        else               v = gmax1[r * 128 + f];
        gl[k] = v;
    }
    __syncthreads();
    {
        int j = threadIdx.x;
        float acc = lb1[j];
        for (int k = 0; k < 512; ++k) acc += gl[k] * lW1[k * 256 + j];
        hb[j] = fmaxf(acc, 0.f);
    }
    __syncthreads();
    {
        int c = threadIdx.x & 15, ch = threadIdx.x >> 4;
        float p = 0.f;
        #pragma unroll
        for (int j2 = 0; j2 < 16; ++j2) p += hb[ch * 16 + j2] * lW2[(ch * 16 + j2) * 16 + c];
        part[threadIdx.x] = p;
    }
    __syncthreads();
    if (threadIdx.x < 16) {
        float s = lb2[threadIdx.x];
        #pragma unroll
        for (int ch2 = 0; ch2 < 16; ++ch2) s += part[ch2 * 16 + threadIdx.x];
        out[r * 16 + threadIdx.x] = s;
    }
}

extern "C" void kernel_launch(void* const* d_in, const int* in_sizes, int n_in,
                              void* d_out, int out_size, void* d_ws, size_t ws_size,
                              hipStream_t stream) {
    const float* x    = (const float*)d_in[0];
    const int*   ei   = (const int*)d_in[1];
    const int*   batch= (const int*)d_in[2];
    const float* W1   = (const float*)d_in[3];
    const float* b1   = (const float*)d_in[4];
    const float* W2   = (const float*)d_in[5];
    const float* b2   = (const float*)d_in[6];
    const float* lW1  = (const float*)d_in[7];
    const float* lb1  = (const float*)d_in[8];
    const float* lW2  = (const float*)d_in[9];
    const float* lb2  = (const float*)d_in[10];
    float* out = (float*)d_out;

    // workspace layout (4-byte units)
    float* bufA   = (float*)d_ws;                      // N*H : h
    float* bufB   = bufA + (size_t)NN * HH;            // N*H : x0
    float* dis    = bufB + (size_t)NN * HH;            // N (padded 50176)
    float* gsum0  = dis + 50176;
    float* gmax0  = gsum0 + GG * HH;
    float* gsum1  = gmax0 + GG * HH;
    float* gmax1  = gsum1 + GG * HH;
    float* cnt    = gmax1 + GG * HH;                   // G
    int*   deg    = (int*)(cnt + GG);                  // N (padded 50176)
    int*   offs   = deg + 50176;                       // N row_start
    int*   cursor = offs + 50176;                      // N
    int*   bsum   = cursor + 50176;                    // 256
    int2*  adj    = (int2*)(bsum + 256);               // E packed (src, norm)

    // ---- CSR build ----
    hipMemsetAsync(deg, 0, 50176 * sizeof(int), stream);
    k_deg<<<(EE + 255) / 256, 256, 0, stream>>>(ei, deg);
    k_dis<<<(NN + 255) / 256, 256, 0, stream>>>(deg, dis);
    k_scan1<<<NBLK_SCAN, 256, 0, stream>>>(deg, offs, bsum);
    k_scan2<<<1, 256, 0, stream>>>(bsum);
    k_scan3<<<NBLK_SCAN, 256, 0, stream>>>(offs, bsum, cursor);
    k_fill<<<(EE + 255) / 256, 256, 0, stream>>>(ei, dis, cursor, adj);

    // ---- zero pool accumulators (contiguous) ----
    hipMemsetAsync(gsum0, 0, (size_t)(4 * GG * HH + GG) * sizeof(float), stream);

    // ---- conv1 ----
    k_gemm<<<NN / 16, 256, 0, stream>>>(x, W1, bufA);
    k_conv<<<NN / 4, 256, 0, stream>>>(bufA, adj, offs, deg, dis, b1, batch,
                                       bufB, gsum0, gmax0, cnt, 3);
    // ---- conv2 ----
    k_gemm<<<NN / 16, 256, 0, stream>>>(bufB, W2, bufA);
    k_conv<<<NN / 4, 256, 0, stream>>>(bufA, adj, offs, deg, dis, b2, batch,
                                       bufB, gsum1, gmax1, cnt, 0);

    // ---- MLP head ----
    k_mlp<<<GG, 256, 0, stream>>>(gsum0, gmax0, gsum1, gmax1, cnt, lW1, lb1, lW2, lb2, out);
}

// Round 4
// 253.824 us; speedup vs baseline: 6.6604x; 1.4498x over previous
//
#include <hip/hip_runtime.h>
#include <hip/hip_bf16.h>

#define NN 50000
#define EE 800000
#define DD 128
#define HH 128
#define CC 16
#define GG 512
#define NBLK_SCAN 196   // ceil(50000/256)
#define NPAD 50176      // padded rows for bf16 feature buffers
#define GEMM_BLOCKS 782 // ceil(50000/64)

typedef __attribute__((ext_vector_type(8))) short short8v;
typedef __attribute__((ext_vector_type(8))) unsigned short ushort8v;
typedef __attribute__((ext_vector_type(4))) float f32x4;

__device__ inline unsigned short f2bf(float x) {  // RNE
    unsigned int u = __float_as_uint(x);
    u += 0x7fffu + ((u >> 16) & 1u);
    return (unsigned short)(u >> 16);
}
__device__ inline float bf2f(unsigned int lo16) { return __uint_as_float(lo16 << 16); }

// ---------------- degree (int, incoming edges only) ----------------
__global__ __launch_bounds__(256) void k_deg(const int* __restrict__ ei, int* __restrict__ deg) {
    int e = blockIdx.x * 256 + threadIdx.x;
    if (e < EE) atomicAdd(&deg[ei[EE + e]], 1);
}

__global__ __launch_bounds__(256) void k_dis(const int* __restrict__ deg, float* __restrict__ dis) {
    int i = blockIdx.x * 256 + threadIdx.x;
    if (i < NN) dis[i] = rsqrtf((float)deg[i] + 1.0f);  // +1 self loop
}

// ---------------- 2-level exclusive scan of deg -> row_start ----------------
__global__ __launch_bounds__(256) void k_scan1(const int* __restrict__ deg,
                                               int* __restrict__ offs, int* __restrict__ bsum) {
    __shared__ int tmp[256];
    int i = blockIdx.x * 256 + threadIdx.x;
    int v = (i < NN) ? deg[i] : 0;
    tmp[threadIdx.x] = v;
    __syncthreads();
    for (int off = 1; off < 256; off <<= 1) {
        int t = (threadIdx.x >= off) ? tmp[threadIdx.x - off] : 0;
        __syncthreads();
        tmp[threadIdx.x] += t;
        __syncthreads();
    }
    if (i < NN) offs[i] = tmp[threadIdx.x] - v;  // exclusive
    if (threadIdx.x == 255) bsum[blockIdx.x] = tmp[255];
}

__global__ __launch_bounds__(256) void k_scan2(int* __restrict__ bsum) {
    __shared__ int tmp[256];
    int v = (threadIdx.x < NBLK_SCAN) ? bsum[threadIdx.x] : 0;
    tmp[threadIdx.x] = v;
    __syncthreads();
    for (int off = 1; off < 256; off <<= 1) {
        int t = (threadIdx.x >= off) ? tmp[threadIdx.x - off] : 0;
        __syncthreads();
        tmp[threadIdx.x] += t;
        __syncthreads();
    }
    bsum[threadIdx.x] = tmp[threadIdx.x] - v;  // exclusive
}

__global__ __launch_bounds__(256) void k_scan3(int* __restrict__ offs, const int* __restrict__ bsum,
                                               int* __restrict__ cursor) {
    int i = blockIdx.x * 256 + threadIdx.x;
    if (i < NN) {
        int v = offs[i] + bsum[blockIdx.x];
        offs[i] = v;
        cursor[i] = v;
    }
}

// ---------------- CSR fill: packed (src, norm) per incoming edge ----------------
__global__ __launch_bounds__(256) void k_fill(const int* __restrict__ ei, const float* __restrict__ dis,
                                              int* __restrict__ cursor, int2* __restrict__ adj) {
    int e = blockIdx.x * 256 + threadIdx.x;
    if (e >= EE) return;
    int s = ei[e];
    int d = ei[EE + e];
    int pos = atomicAdd(&cursor[d], 1);
    adj[pos] = make_int2(s, __float_as_int(dis[s] * dis[d]));
}

// ---------------- W -> MFMA fragment-linear bf16 pack ----------------
// frag idx = (kt*8 + ct)*64 + lane; elem j -> W[kt*32 + (lane>>4)*8 + j][ct*16 + (lane&15)]
__global__ __launch_bounds__(256) void k_wfrag(const float* __restrict__ W, unsigned short* __restrict__ Wf) {
    for (int idx = threadIdx.x; idx < 2048; idx += 256) {
        int lane = idx & 63, ct = (idx >> 6) & 7, kt = idx >> 9;
        int col = ct * 16 + (lane & 15);
        int k0 = kt * 32 + (lane >> 4) * 8;
        ushort8v v;
        #pragma unroll
        for (int j = 0; j < 8; ++j) v[j] = f2bf(W[(k0 + j) * 128 + col]);
        *(ushort8v*)(Wf + idx * 8) = v;
    }
}

// ---------------- MFMA GEMM: O[NPAD,128](bf16) = A[N,128] @ W ----------------
// 256 thr = 4 waves, 64 rows/block; A from f32 (af32=1, clamped at NN) or bf16 buffer
__global__ __launch_bounds__(256) void k_gemm(const float* __restrict__ Af,
                                              const unsigned short* __restrict__ Ab,
                                              const unsigned short* __restrict__ Wf,
                                              unsigned short* __restrict__ O,
                                              int af32) {
    __shared__ unsigned short Wl[16384];  // 32 KB
    #pragma unroll
    for (int idx = threadIdx.x; idx < 2048; idx += 256)
        *(ushort8v*)(Wl + idx * 8) = *(const ushort8v*)(Wf + idx * 8);
    __syncthreads();

    int wid = threadIdx.x >> 6, lane = threadIdx.x & 63;
    int b = lane >> 4;
    int row = blockIdx.x * 64 + wid * 16 + (lane & 15);

    short8v a[4];
    if (af32) {
        int r = min(row, NN - 1);
        const float* ap = Af + (size_t)r * 128 + b * 8;
        #pragma unroll
        for (int kt = 0; kt < 4; ++kt) {
            float4 f0 = *(const float4*)(ap + kt * 32);
            float4 f1 = *(const float4*)(ap + kt * 32 + 4);
            short8v v;
            v[0] = (short)f2bf(f0.x); v[1] = (short)f2bf(f0.y);
            v[2] = (short)f2bf(f0.z); v[3] = (short)f2bf(f0.w);
            v[4] = (short)f2bf(f1.x); v[5] = (short)f2bf(f1.y);
            v[6] = (short)f2bf(f1.z); v[7] = (short)f2bf(f1.w);
            a[kt] = v;
        }
    } else {
        const unsigned short* ap = Ab + (size_t)row * 128 + b * 8;
        #pragma unroll
        for (int kt = 0; kt < 4; ++kt) a[kt] = *(const short8v*)(ap + kt * 32);
    }

    f32x4 z = 0.0f;
    f32x4 acc[8] = {z, z, z, z, z, z, z, z};
    #pragma unroll
    for (int kt = 0; kt < 4; ++kt) {
        #pragma unroll
        for (int ct = 0; ct < 8; ++ct) {
            short8v bfrag = *(const short8v*)(Wl + ((kt * 8 + ct) * 64 + lane) * 8);
            acc[ct] = __builtin_amdgcn_mfma_f32_16x16x32_bf16(a[kt], bfrag, acc[ct], 0, 0, 0);
        }
    }

    // C/D: row = (lane>>4)*4 + j, col = ct*16 + (lane&15)   [m89-verified]
    int orow = blockIdx.x * 64 + wid * 16 + b * 4;
    unsigned short* op = O + (size_t)orow * 128 + (lane & 15);
    #pragma unroll
    for (int j = 0; j < 4; ++j) {
        #pragma unroll
        for (int ct = 0; ct < 8; ++ct)
            op[(size_t)j * 128 + ct * 16] = f2bf(acc[ct][j]);
    }
}

// ---------------- fused gather conv + self + bias + relu + pool (bf16 h) ----------------
__global__ __launch_bounds__(256) void k_conv(const unsigned short* __restrict__ h,
                                              const int2* __restrict__ adj,
                                              const int* __restrict__ row_start,
                                              const int* __restrict__ deg,
                                              const float* __restrict__ dis,
                                              const float* __restrict__ bias,
                                              const int* __restrict__ batch,
                                              unsigned short* __restrict__ xout,
                                              float* __restrict__ gsum,
                                              float* __restrict__ gmax,
                                              float* __restrict__ cnt,
                                              int flags) {  // 1 = write xout, 2 = count
    __shared__ float lacc[4][128];
    __shared__ int lb[4];
    int wid = threadIdx.x >> 6;
    int lane = threadIdx.x & 63;
    int node = blockIdx.x * 4 + wid;
    int f = lane * 2;
    float di = dis[node];
    unsigned int hv = *(const unsigned int*)(h + (size_t)node * 128 + f);
    float2 bv = *(const float2*)(bias + f);
    float accx = bf2f(hv & 0xffffu) * di * di + bv.x;
    float accy = bf2f(hv >> 16)    * di * di + bv.y;
    int rs = row_start[node];
    int n  = deg[node];
    const int2* ap = adj + rs;
    if (n > 0) {
        for (int k = 0; k < n; k += 8) {
            int2 pk[8];
            #pragma unroll
            for (int j = 0; j < 8; ++j) pk[j] = ap[min(k + j, n - 1)];
            #pragma unroll
            for (int j = 0; j < 8; ++j) {
                unsigned int v = *(const unsigned int*)(h + (size_t)pk[j].x * 128 + f);
                float w = (k + j < n) ? __int_as_float(pk[j].y) : 0.f;
                accx += bf2f(v & 0xffffu) * w;
                accy += bf2f(v >> 16)    * w;
            }
        }
    }
    accx = fmaxf(accx, 0.f);
    accy = fmaxf(accy, 0.f);
    if (flags & 1)
        *(unsigned int*)(xout + (size_t)node * 128 + f) =
            (unsigned int)f2bf(accx) | ((unsigned int)f2bf(accy) << 16);

    // block-level pool pre-reduction (batch is sorted -> runs of equal group)
    lacc[wid][f]     = accx;
    lacc[wid][f + 1] = accy;
    if (lane == 0) lb[wid] = batch[node];
    __syncthreads();
    if (wid == 0) {
        float sx = lacc[0][f], sy = lacc[0][f + 1];
        float mx = sx, my = sy;
        int cur = lb[0], run = 1;
        #pragma unroll
        for (int w = 1; w < 4; ++w) {
            float ax = lacc[w][f], ay = lacc[w][f + 1];
            if (lb[w] == cur) {
                sx += ax; sy += ay;
                mx = fmaxf(mx, ax); my = fmaxf(my, ay);
                run++;
            } else {
                atomicAdd(&gsum[cur * 128 + f],     sx);
                atomicAdd(&gsum[cur * 128 + f + 1], sy);
                atomicMax((int*)&gmax[cur * 128 + f],     __float_as_int(mx));
                atomicMax((int*)&gmax[cur * 128 + f + 1], __float_as_int(my));
                if (lane == 0 && (flags & 2)) atomicAdd(cnt + cur, (float)run);
                sx = ax; sy = ay; mx = ax; my = ay; cur = lb[w]; run = 1;
            }
        }
        atomicAdd(&gsum[cur * 128 + f],     sx);
        atomicAdd(&gsum[cur * 128 + f + 1], sy);
        atomicMax((int*)&gmax[cur * 128 + f],     __float_as_int(mx));
        atomicMax((int*)&gmax[cur * 128 + f + 1], __float_as_int(my));
        if (lane == 0 && (flags & 2)) atomicAdd(cnt + cur, (float)run);
    }
}

// ---------------- final MLP: one block per graph ----------------
__global__ __launch_bounds__(256) void k_mlp(const float* __restrict__ gsum0,
                                             const float* __restrict__ gmax0,
                                             const float* __restrict__ gsum1,
                                             const float* __restrict__ gmax1,
                                             const float* __restrict__ cnt,
                                             const float* __restrict__ lW1,
                                             const float* __restrict__ lb1,
                                             const float* __restrict__ lW2,
                                             const float* __restrict__ lb2,
                                             float* __restrict__ out) {
    __shared__ float gl[512];
    __shared__ float hb[256];
    __shared__ float part[256];
    int r = blockIdx.x;
    float inv = 1.0f / fmaxf(cnt[r], 1.0f);
    for (int k = threadIdx.x; k < 512; k += 256) {
        int seg = k >> 7, f = k & 127;
        float v;
        if (seg == 0)      v = gsum0[r * 128 + f] * inv;
        else if (seg == 1) v = gmax0[r * 128 + f];
        else if (seg == 2) v = gsum1[r * 128 + f] * inv;
        else               v = gmax1[r * 128 + f];
        gl[k] = v;
    }
    __syncthreads();
    {
        int j = threadIdx.x;
        float acc = lb1[j];
        for (int k = 0; k < 512; ++k) acc += gl[k] * lW1[k * 256 + j];
        hb[j] = fmaxf(acc, 0.f);
    }
    __syncthreads();
    {
        int c = threadIdx.x & 15, ch = threadIdx.x >> 4;
        float p = 0.f;
        #pragma unroll
        for (int j2 = 0; j2 < 16; ++j2) p += hb[ch * 16 + j2] * lW2[(ch * 16 + j2) * 16 + c];
        part[threadIdx.x] = p;
    }
    __syncthreads();
    if (threadIdx.x < 16) {
        float s = lb2[threadIdx.x];
        #pragma unroll
        for (int ch2 = 0; ch2 < 16; ++ch2) s += part[ch2 * 16 + threadIdx.x];
        out[r * 16 + threadIdx.x] = s;
    }
}

extern "C" void kernel_launch(void* const* d_in, const int* in_sizes, int n_in,
                              void* d_out, int out_size, void* d_ws, size_t ws_size,
                              hipStream_t stream) {
    const float* x    = (const float*)d_in[0];
    const int*   ei   = (const int*)d_in[1];
    const int*   batch= (const int*)d_in[2];
    const float* W1   = (const float*)d_in[3];
    const float* b1   = (const float*)d_in[4];
    const float* W2   = (const float*)d_in[5];
    const float* b2   = (const float*)d_in[6];
    const float* lW1  = (const float*)d_in[7];
    const float* lb1  = (const float*)d_in[8];
    const float* lW2  = (const float*)d_in[9];
    const float* lb2  = (const float*)d_in[10];
    float* out = (float*)d_out;

    // ---- workspace layout ----
    unsigned short* hbuf = (unsigned short*)d_ws;          // NPAD*128 bf16 (h1, then h2)
    unsigned short* x0b  = hbuf + (size_t)NPAD * 128;      // NPAD*128 bf16 (x0)
    unsigned short* wf1  = x0b + (size_t)NPAD * 128;       // 16384 bf16 frag-packed W1
    unsigned short* wf2  = wf1 + 16384;                    // 16384
    float* dis   = (float*)(wf2 + 16384);                  // NPAD f32
    float* gsum0 = dis + NPAD;
    float* gmax0 = gsum0 + GG * HH;
    float* gsum1 = gmax0 + GG * HH;
    float* gmax1 = gsum1 + GG * HH;
    float* cnt   = gmax1 + GG * HH;                        // G
    int*   deg    = (int*)(cnt + GG);                      // NPAD
    int*   offs   = deg + NPAD;
    int*   cursor = offs + NPAD;
    int*   bsum   = cursor + NPAD;                         // 256
    int2*  adj    = (int2*)(bsum + 256);                   // E packed (src, norm)

    // ---- CSR build ----
    hipMemsetAsync(deg, 0, NPAD * sizeof(int), stream);
    k_deg<<<(EE + 255) / 256, 256, 0, stream>>>(ei, deg);
    k_dis<<<(NN + 255) / 256, 256, 0, stream>>>(deg, dis);
    k_scan1<<<NBLK_SCAN, 256, 0, stream>>>(deg, offs, bsum);
    k_scan2<<<1, 256, 0, stream>>>(bsum);
    k_scan3<<<NBLK_SCAN, 256, 0, stream>>>(offs, bsum, cursor);
    k_fill<<<(EE + 255) / 256, 256, 0, stream>>>(ei, dis, cursor, adj);

    // ---- W fragment packs + zero pools ----
    k_wfrag<<<1, 256, 0, stream>>>(W1, wf1);
    k_wfrag<<<1, 256, 0, stream>>>(W2, wf2);
    hipMemsetAsync(gsum0, 0, (size_t)(4 * GG * HH + GG) * sizeof(float), stream);

    // ---- conv1 ----
    k_gemm<<<GEMM_BLOCKS, 256, 0, stream>>>(x, (const unsigned short*)nullptr, wf1, hbuf, 1);
    k_conv<<<NN / 4, 256, 0, stream>>>(hbuf, adj, offs, deg, dis, b1, batch,
                                       x0b, gsum0, gmax0, cnt, 3);
    // ---- conv2 ----
    k_gemm<<<GEMM_BLOCKS, 256, 0, stream>>>((const float*)nullptr, x0b, wf2, hbuf, 0);
    k_conv<<<NN / 4, 256, 0, stream>>>(hbuf, adj, offs, deg, dis, b2, batch,
                                       x0b, gsum1, gmax1, cnt, 0);

    // ---- MLP head ----
    k_mlp<<<GG, 256, 0, stream>>>(gsum0, gmax0, gsum1, gmax1, cnt, lW1, lb1, lW2, lb2, out);
}

// Round 5
// 236.645 us; speedup vs baseline: 7.1439x; 1.0726x over previous
//
#include <hip/hip_runtime.h>
#include <hip/hip_bf16.h>

#define NN 50000
#define EE 800000
#define DD 128
#define HH 128
#define CC 16
#define GG 512
#define NBLK_SCAN 196   // ceil(50000/256)
#define NPAD 50176      // padded rows for bf16 feature buffers
#define GEMM_BLOCKS 782 // ceil(50000/64)

typedef __attribute__((ext_vector_type(8))) short short8v;
typedef __attribute__((ext_vector_type(8))) unsigned short ushort8v;
typedef __attribute__((ext_vector_type(4))) float f32x4;

__device__ inline unsigned short f2bf(float x) {  // RNE
    unsigned int u = __float_as_uint(x);
    u += 0x7fffu + ((u >> 16) & 1u);
    return (unsigned short)(u >> 16);
}

// ---------------- degree (int, incoming edges only) ----------------
__global__ __launch_bounds__(256) void k_deg(const int* __restrict__ ei, int* __restrict__ deg) {
    int e = blockIdx.x * 256 + threadIdx.x;
    if (e < EE) atomicAdd(&deg[ei[EE + e]], 1);
}

// ---------------- scan level 1 (+ fused dis = rsqrt(deg+1)) ----------------
__global__ __launch_bounds__(256) void k_scan1(const int* __restrict__ deg,
                                               int* __restrict__ offs, int* __restrict__ bsum,
                                               float* __restrict__ dis) {
    __shared__ int tmp[256];
    int i = blockIdx.x * 256 + threadIdx.x;
    int v = (i < NN) ? deg[i] : 0;
    if (i < NN) dis[i] = rsqrtf((float)v + 1.0f);  // +1 self loop
    tmp[threadIdx.x] = v;
    __syncthreads();
    for (int off = 1; off < 256; off <<= 1) {
        int t = (threadIdx.x >= off) ? tmp[threadIdx.x - off] : 0;
        __syncthreads();
        tmp[threadIdx.x] += t;
        __syncthreads();
    }
    if (i < NN) offs[i] = tmp[threadIdx.x] - v;  // exclusive
    if (threadIdx.x == 255) bsum[blockIdx.x] = tmp[255];
}

__global__ __launch_bounds__(256) void k_scan2(int* __restrict__ bsum) {
    __shared__ int tmp[256];
    int v = (threadIdx.x < NBLK_SCAN) ? bsum[threadIdx.x] : 0;
    tmp[threadIdx.x] = v;
    __syncthreads();
    for (int off = 1; off < 256; off <<= 1) {
        int t = (threadIdx.x >= off) ? tmp[threadIdx.x - off] : 0;
        __syncthreads();
        tmp[threadIdx.x] += t;
        __syncthreads();
    }
    bsum[threadIdx.x] = tmp[threadIdx.x] - v;  // exclusive
}

__global__ __launch_bounds__(256) void k_scan3(int* __restrict__ offs, const int* __restrict__ bsum,
                                               int* __restrict__ cursor) {
    int i = blockIdx.x * 256 + threadIdx.x;
    if (i < NN) {
        int v = offs[i] + bsum[blockIdx.x];
        offs[i] = v;
        cursor[i] = v;
    }
}

// ---------------- CSR fill: ONE packed uint per edge: src<<16 | bf16(norm) ----------------
__global__ __launch_bounds__(256) void k_fill(const int* __restrict__ ei, const float* __restrict__ dis,
                                              int* __restrict__ cursor, unsigned int* __restrict__ adj) {
    int e = blockIdx.x * 256 + threadIdx.x;
    if (e >= EE) return;
    int s = ei[e];
    int d = ei[EE + e];
    int pos = atomicAdd(&cursor[d], 1);
    adj[pos] = ((unsigned int)s << 16) | (unsigned int)f2bf(dis[s] * dis[d]);
}

// ---------------- W -> MFMA fragment-linear bf16 pack (both weights, 1 launch) ----------------
__global__ __launch_bounds__(256) void k_wfrag(const float* __restrict__ W1, const float* __restrict__ W2,
                                               unsigned short* __restrict__ Wf) {
    const float* W = blockIdx.x ? W2 : W1;
    unsigned short* o = Wf + blockIdx.x * 16384;
    for (int idx = threadIdx.x; idx < 2048; idx += 256) {
        int lane = idx & 63, ct = (idx >> 6) & 7, kt = idx >> 9;
        int col = ct * 16 + (lane & 15);
        int k0 = kt * 32 + (lane >> 4) * 8;
        ushort8v v;
        #pragma unroll
        for (int j = 0; j < 8; ++j) v[j] = f2bf(W[(k0 + j) * 128 + col]);
        *(ushort8v*)(o + idx * 8) = v;
    }
}

// ---------------- MFMA GEMM: O[NPAD,128](bf16) = A[N,128] @ W ----------------
__global__ __launch_bounds__(256) void k_gemm(const float* __restrict__ Af,
                                              const unsigned short* __restrict__ Ab,
                                              const unsigned short* __restrict__ Wf,
                                              unsigned short* __restrict__ O,
                                              int af32) {
    __shared__ unsigned short Wl[16384];  // 32 KB
    #pragma unroll
    for (int idx = threadIdx.x; idx < 2048; idx += 256)
        *(ushort8v*)(Wl + idx * 8) = *(const ushort8v*)(Wf + idx * 8);
    __syncthreads();

    int wid = threadIdx.x >> 6, lane = threadIdx.x & 63;
    int b = lane >> 4;
    int row = blockIdx.x * 64 + wid * 16 + (lane & 15);

    short8v a[4];
    if (af32) {
        int r = min(row, NN - 1);
        const float* ap = Af + (size_t)r * 128 + b * 8;
        #pragma unroll
        for (int kt = 0; kt < 4; ++kt) {
            float4 f0 = *(const float4*)(ap + kt * 32);
            float4 f1 = *(const float4*)(ap + kt * 32 + 4);
            short8v v;
            v[0] = (short)f2bf(f0.x); v[1] = (short)f2bf(f0.y);
            v[2] = (short)f2bf(f0.z); v[3] = (short)f2bf(f0.w);
            v[4] = (short)f2bf(f1.x); v[5] = (short)f2bf(f1.y);
            v[6] = (short)f2bf(f1.z); v[7] = (short)f2bf(f1.w);
            a[kt] = v;
        }
    } else {
        const unsigned short* ap = Ab + (size_t)row * 128 + b * 8;
        #pragma unroll
        for (int kt = 0; kt < 4; ++kt) a[kt] = *(const short8v*)(ap + kt * 32);
    }

    f32x4 z = 0.0f;
    f32x4 acc[8] = {z, z, z, z, z, z, z, z};
    #pragma unroll
    for (int kt = 0; kt < 4; ++kt) {
        #pragma unroll
        for (int ct = 0; ct < 8; ++ct) {
            short8v bfrag = *(const short8v*)(Wl + ((kt * 8 + ct) * 64 + lane) * 8);
            acc[ct] = __builtin_amdgcn_mfma_f32_16x16x32_bf16(a[kt], bfrag, acc[ct], 0, 0, 0);
        }
    }

    // C/D: row = (lane>>4)*4 + j, col = ct*16 + (lane&15)   [m89-verified]
    int orow = blockIdx.x * 64 + wid * 16 + b * 4;
    unsigned short* op = O + (size_t)orow * 128 + (lane & 15);
    #pragma unroll
    for (int j = 0; j < 4; ++j) {
        #pragma unroll
        for (int ct = 0; ct < 8; ++ct)
            op[(size_t)j * 128 + ct * 16] = f2bf(acc[ct][j]);
    }
}

// ---------------- fused gather conv + self + bias + relu + pool (bf16 h, packed adj) ----------------
// one wave per dst node, 2 features per lane; 16-deep unroll with adj prefetch
__global__ __launch_bounds__(256) void k_conv(const unsigned short* __restrict__ h,
                                              const unsigned int* __restrict__ adj,
                                              const int* __restrict__ row_start,
                                              const int* __restrict__ deg,
                                              const float* __restrict__ dis,
                                              const float* __restrict__ bias,
                                              const int* __restrict__ batch,
                                              unsigned short* __restrict__ xout,
                                              float* __restrict__ gsum,
                                              float* __restrict__ gmax,
                                              float* __restrict__ cnt,
                                              int flags) {  // 1 = write xout, 2 = count
    __shared__ float lacc[4][128];
    __shared__ int lb[4];
    int wid = threadIdx.x >> 6;
    int lane = threadIdx.x & 63;
    int node = blockIdx.x * 4 + wid;
    int f = lane * 2;
    float di = dis[node];
    unsigned int hv = *(const unsigned int*)(h + (size_t)node * 128 + f);
    float2 bv = *(const float2*)(bias + f);
    float accx = __uint_as_float(hv << 16)         * di * di + bv.x;
    float accy = __uint_as_float(hv & 0xffff0000u) * di * di + bv.y;
    int rs = row_start[node];
    int n  = deg[node];
    const unsigned int* ap = adj + rs;
    if (n > 0) {
        unsigned int pk[16], pn[16];
        #pragma unroll
        for (int j = 0; j < 16; ++j) pk[j] = ap[j];   // adj padded: OOB reads harmless (w=0)
        for (int k = 0;;) {
            int more = (k + 16) < n;
            if (more) {
                #pragma unroll
                for (int j = 0; j < 16; ++j) pn[j] = ap[k + 16 + j];
            }
            #pragma unroll
            for (int j = 0; j < 16; ++j) {
                unsigned int e = pk[j];
                unsigned int v = *(const unsigned int*)(h + (size_t)(e >> 16) * 128 + f);
                float w = (k + j < n) ? __uint_as_float(e << 16) : 0.f;
                accx = fmaf(__uint_as_float(v << 16),         w, accx);
                accy = fmaf(__uint_as_float(v & 0xffff0000u), w, accy);
            }
            if (!more) break;
            k += 16;
            #pragma unroll
            for (int j = 0; j < 16; ++j) pk[j] = pn[j];
        }
    }
    accx = fmaxf(accx, 0.f);
    accy = fmaxf(accy, 0.f);
    if (flags & 1)
        *(unsigned int*)(xout + (size_t)node * 128 + f) =
            (unsigned int)f2bf(accx) | ((unsigned int)f2bf(accy) << 16);

    // block-level pool pre-reduction (batch is sorted -> runs of equal group)
    lacc[wid][f]     = accx;
    lacc[wid][f + 1] = accy;
    if (lane == 0) lb[wid] = batch[node];
    __syncthreads();
    if (wid == 0) {
        float sx = lacc[0][f], sy = lacc[0][f + 1];
        float mx = sx, my = sy;
        int cur = lb[0], run = 1;
        #pragma unroll
        for (int w = 1; w < 4; ++w) {
            float ax = lacc[w][f], ay = lacc[w][f + 1];
            if (lb[w] == cur) {
                sx += ax; sy += ay;
                mx = fmaxf(mx, ax); my = fmaxf(my, ay);
                run++;
            } else {
                atomicAdd(&gsum[cur * 128 + f],     sx);
                atomicAdd(&gsum[cur * 128 + f + 1], sy);
                atomicMax((int*)&gmax[cur * 128 + f],     __float_as_int(mx));
                atomicMax((int*)&gmax[cur * 128 + f + 1], __float_as_int(my));
                if (lane == 0 && (flags & 2)) atomicAdd(cnt + cur, (float)run);
                sx = ax; sy = ay; mx = ax; my = ay; cur = lb[w]; run = 1;
            }
        }
        atomicAdd(&gsum[cur * 128 + f],     sx);
        atomicAdd(&gsum[cur * 128 + f + 1], sy);
        atomicMax((int*)&gmax[cur * 128 + f],     __float_as_int(mx));
        atomicMax((int*)&gmax[cur * 128 + f + 1], __float_as_int(my));
        if (lane == 0 && (flags & 2)) atomicAdd(cnt + cur, (float)run);
    }
}

// ---------------- final MLP: one block per graph ----------------
__global__ __launch_bounds__(256) void k_mlp(const float* __restrict__ gsum0,
                                             const float* __restrict__ gmax0,
                                             const float* __restrict__ gsum1,
                                             const float* __restrict__ gmax1,
                                             const float* __restrict__ cnt,
                                             const float* __restrict__ lW1,
                                             const float* __restrict__ lb1,
                                             const float* __restrict__ lW2,
                                             const float* __restrict__ lb2,
                                             float* __restrict__ out) {
    __shared__ float gl[512];
    __shared__ float hb[256];
    __shared__ float part[256];
    int r = blockIdx.x;
    float inv = 1.0f / fmaxf(cnt[r], 1.0f);
    for (int k = threadIdx.x; k < 512; k += 256) {
        int seg = k >> 7, f = k & 127;
        float v;
        if (seg == 0)      v = gsum0[r * 128 + f] * inv;
        else if (seg == 1) v = gmax0[r * 128 + f];
        else if (seg == 2) v = gsum1[r * 128 + f] * inv;
        else               v = gmax1[r * 128 + f];
        gl[k] = v;
    }
    __syncthreads();
    {
        int j = threadIdx.x;
        float acc = lb1[j];
        for (int k = 0; k < 512; ++k) acc += gl[k] * lW1[k * 256 + j];
        hb[j] = fmaxf(acc, 0.f);
    }
    __syncthreads();
    {
        int c = threadIdx.x & 15, ch = threadIdx.x >> 4;
        float p = 0.f;
        #pragma unroll
        for (int j2 = 0; j2 < 16; ++j2) p += hb[ch * 16 + j2] * lW2[(ch * 16 + j2) * 16 + c];
        part[threadIdx.x] = p;
    }
    __syncthreads();
    if (threadIdx.x < 16) {
        float s = lb2[threadIdx.x];
        #pragma unroll
        for (int ch2 = 0; ch2 < 16; ++ch2) s += part[ch2 * 16 + threadIdx.x];
        out[r * 16 + threadIdx.x] = s;
    }
}

extern "C" void kernel_launch(void* const* d_in, const int* in_sizes, int n_in,
                              void* d_out, int out_size, void* d_ws, size_t ws_size,
                              hipStream_t stream) {
    const float* x    = (const float*)d_in[0];
    const int*   ei   = (const int*)d_in[1];
    const int*   batch= (const int*)d_in[2];
    const float* W1   = (const float*)d_in[3];
    const float* b1   = (const float*)d_in[4];
    const float* W2   = (const float*)d_in[5];
    const float* b2   = (const float*)d_in[6];
    const float* lW1  = (const float*)d_in[7];
    const float* lb1  = (const float*)d_in[8];
    const float* lW2  = (const float*)d_in[9];
    const float* lb2  = (const float*)d_in[10];
    float* out = (float*)d_out;

    // ---- workspace layout ----
    unsigned short* hbuf = (unsigned short*)d_ws;          // NPAD*128 bf16 (h1, then h2)
    unsigned short* x0b  = hbuf + (size_t)NPAD * 128;      // NPAD*128 bf16 (x0)
    unsigned short* wf   = x0b + (size_t)NPAD * 128;       // 2*16384 bf16 frag-packed W1,W2
    float* dis   = (float*)(wf + 32768);                   // NPAD f32
    float* gsum0 = dis + NPAD;
    float* gmax0 = gsum0 + GG * HH;
    float* gsum1 = gmax0 + GG * HH;
    float* gmax1 = gsum1 + GG * HH;
    float* cnt   = gmax1 + GG * HH;                        // G
    int*   deg    = (int*)(cnt + GG);                      // NPAD
    int*   offs   = deg + NPAD;
    int*   cursor = offs + NPAD;
    int*   bsum   = cursor + NPAD;                         // 256
    unsigned int* adj = (unsigned int*)(bsum + 256);       // E packed + 64 pad

    // ---- CSR build ----
    hipMemsetAsync(deg, 0, NPAD * sizeof(int), stream);
    k_deg<<<(EE + 255) / 256, 256, 0, stream>>>(ei, deg);
    k_scan1<<<NBLK_SCAN, 256, 0, stream>>>(deg, offs, bsum, dis);
    k_scan2<<<1, 256, 0, stream>>>(bsum);
    k_scan3<<<NBLK_SCAN, 256, 0, stream>>>(offs, bsum, cursor);
    k_fill<<<(EE + 255) / 256, 256, 0, stream>>>(ei, dis, cursor, adj);

    // ---- W fragment packs + zero pools ----
    k_wfrag<<<2, 256, 0, stream>>>(W1, W2, wf);
    hipMemsetAsync(gsum0, 0, (size_t)(4 * GG * HH + GG) * sizeof(float), stream);

    // ---- conv1 ----
    k_gemm<<<GEMM_BLOCKS, 256, 0, stream>>>(x, (const unsigned short*)nullptr, wf, hbuf, 1);
    k_conv<<<NN / 4, 256, 0, stream>>>(hbuf, adj, offs, deg, dis, b1, batch,
                                       x0b, gsum0, gmax0, cnt, 3);
    // ---- conv2 ----
    k_gemm<<<GEMM_BLOCKS, 256, 0, stream>>>((const float*)nullptr, x0b, wf + 16384, hbuf, 0);
    k_conv<<<NN / 4, 256, 0, stream>>>(hbuf, adj, offs, deg, dis, b2, batch,
                                       x0b, gsum1, gmax1, cnt, 0);

    // ---- MLP head ----
    k_mlp<<<GG, 256, 0, stream>>>(gsum0, gmax0, gsum1, gmax1, cnt, lW1, lb1, lW2, lb2, out);
}

// Round 6
// 210.763 us; speedup vs baseline: 8.0212x; 1.1228x over previous
//
#include <hip/hip_runtime.h>
#include <hip/hip_bf16.h>

#define NN 50000
#define EE 800000
#define DD 128
#define HH 128
#define CC 16
#define GG 512
#define NBLK_SCAN 196   // ceil(50000/256)
#define NPAD 50176      // padded rows for bf16 feature buffers
#define GEMM_BLOCKS 782 // ceil(50000/64)

typedef __attribute__((ext_vector_type(8))) short short8v;
typedef __attribute__((ext_vector_type(8))) unsigned short ushort8v;
typedef __attribute__((ext_vector_type(4))) float f32x4;

__device__ inline unsigned short f2bf(float x) {  // RNE
    unsigned int u = __float_as_uint(x);
    u += 0x7fffu + ((u >> 16) & 1u);
    return (unsigned short)(u >> 16);
}

// ---------------- degree (int, incoming edges only) ----------------
__global__ __launch_bounds__(256) void k_deg(const int* __restrict__ ei, int* __restrict__ deg) {
    int e = blockIdx.x * 256 + threadIdx.x;
    if (e < EE) atomicAdd(&deg[ei[EE + e]], 1);
}

// ---------------- scan level 1 (+ fused dis = rsqrt(deg+1)) ----------------
__global__ __launch_bounds__(256) void k_scan1(const int* __restrict__ deg,
                                               int* __restrict__ offs, int* __restrict__ bsum,
                                               float* __restrict__ dis) {
    __shared__ int tmp[256];
    int i = blockIdx.x * 256 + threadIdx.x;
    int v = (i < NN) ? deg[i] : 0;
    if (i < NN) dis[i] = rsqrtf((float)v + 1.0f);  // +1 self loop
    tmp[threadIdx.x] = v;
    __syncthreads();
    for (int off = 1; off < 256; off <<= 1) {
        int t = (threadIdx.x >= off) ? tmp[threadIdx.x - off] : 0;
        __syncthreads();
        tmp[threadIdx.x] += t;
        __syncthreads();
    }
    if (i < NN) offs[i] = tmp[threadIdx.x] - v;  // exclusive
    if (threadIdx.x == 255) bsum[blockIdx.x] = tmp[255];
}

__global__ __launch_bounds__(256) void k_scan2(int* __restrict__ bsum) {
    __shared__ int tmp[256];
    int v = (threadIdx.x < NBLK_SCAN) ? bsum[threadIdx.x] : 0;
    tmp[threadIdx.x] = v;
    __syncthreads();
    for (int off = 1; off < 256; off <<= 1) {
        int t = (threadIdx.x >= off) ? tmp[threadIdx.x - off] : 0;
        __syncthreads();
        tmp[threadIdx.x] += t;
        __syncthreads();
    }
    bsum[threadIdx.x] = tmp[threadIdx.x] - v;  // exclusive
}

__global__ __launch_bounds__(256) void k_scan3(int* __restrict__ offs, const int* __restrict__ bsum,
                                               int* __restrict__ cursor) {
    int i = blockIdx.x * 256 + threadIdx.x;
    if (i < NN) {
        int v = offs[i] + bsum[blockIdx.x];
        offs[i] = v;
        cursor[i] = v;
    }
}

// ---------------- CSR fill: ONE packed uint per edge: src<<16 | bf16(norm) ----------------
__global__ __launch_bounds__(256) void k_fill(const int* __restrict__ ei, const float* __restrict__ dis,
                                              int* __restrict__ cursor, unsigned int* __restrict__ adj) {
    int e = blockIdx.x * 256 + threadIdx.x;
    if (e >= EE) return;
    int s = ei[e];
    int d = ei[EE + e];
    int pos = atomicAdd(&cursor[d], 1);
    adj[pos] = ((unsigned int)s << 16) | (unsigned int)f2bf(dis[s] * dis[d]);
}

// ---------------- W -> MFMA fragment-linear bf16 pack (both weights, 1 launch) ----------------
__global__ __launch_bounds__(256) void k_wfrag(const float* __restrict__ W1, const float* __restrict__ W2,
                                               unsigned short* __restrict__ Wf) {
    const float* W = blockIdx.x ? W2 : W1;
    unsigned short* o = Wf + blockIdx.x * 16384;
    for (int idx = threadIdx.x; idx < 2048; idx += 256) {
        int lane = idx & 63, ct = (idx >> 6) & 7, kt = idx >> 9;
        int col = ct * 16 + (lane & 15);
        int k0 = kt * 32 + (lane >> 4) * 8;
        ushort8v v;
        #pragma unroll
        for (int j = 0; j < 8; ++j) v[j] = f2bf(W[(k0 + j) * 128 + col]);
        *(ushort8v*)(o + idx * 8) = v;
    }
}

// ---------------- MFMA GEMM: O[NPAD,128](bf16) = A[N,128] @ W ----------------
__global__ __launch_bounds__(256) void k_gemm(const float* __restrict__ Af,
                                              const unsigned short* __restrict__ Ab,
                                              const unsigned short* __restrict__ Wf,
                                              unsigned short* __restrict__ O,
                                              int af32) {
    __shared__ unsigned short Wl[16384];  // 32 KB
    #pragma unroll
    for (int idx = threadIdx.x; idx < 2048; idx += 256)
        *(ushort8v*)(Wl + idx * 8) = *(const ushort8v*)(Wf + idx * 8);
    __syncthreads();

    int wid = threadIdx.x >> 6, lane = threadIdx.x & 63;
    int b = lane >> 4;
    int row = blockIdx.x * 64 + wid * 16 + (lane & 15);

    short8v a[4];
    if (af32) {
        int r = min(row, NN - 1);
        const float* ap = Af + (size_t)r * 128 + b * 8;
        #pragma unroll
        for (int kt = 0; kt < 4; ++kt) {
            float4 f0 = *(const float4*)(ap + kt * 32);
            float4 f1 = *(const float4*)(ap + kt * 32 + 4);
            short8v v;
            v[0] = (short)f2bf(f0.x); v[1] = (short)f2bf(f0.y);
            v[2] = (short)f2bf(f0.z); v[3] = (short)f2bf(f0.w);
            v[4] = (short)f2bf(f1.x); v[5] = (short)f2bf(f1.y);
            v[6] = (short)f2bf(f1.z); v[7] = (short)f2bf(f1.w);
            a[kt] = v;
        }
    } else {
        const unsigned short* ap = Ab + (size_t)row * 128 + b * 8;
        #pragma unroll
        for (int kt = 0; kt < 4; ++kt) a[kt] = *(const short8v*)(ap + kt * 32);
    }

    f32x4 z = 0.0f;
    f32x4 acc[8] = {z, z, z, z, z, z, z, z};
    #pragma unroll
    for (int kt = 0; kt < 4; ++kt) {
        #pragma unroll
        for (int ct = 0; ct < 8; ++ct) {
            short8v bfrag = *(const short8v*)(Wl + ((kt * 8 + ct) * 64 + lane) * 8);
            acc[ct] = __builtin_amdgcn_mfma_f32_16x16x32_bf16(a[kt], bfrag, acc[ct], 0, 0, 0);
        }
    }

    // C/D: row = (lane>>4)*4 + j, col = ct*16 + (lane&15)   [m89-verified]
    int orow = blockIdx.x * 64 + wid * 16 + b * 4;
    unsigned short* op = O + (size_t)orow * 128 + (lane & 15);
    #pragma unroll
    for (int j = 0; j < 4; ++j) {
        #pragma unroll
        for (int ct = 0; ct < 8; ++ct)
            op[(size_t)j * 128 + ct * 16] = f2bf(acc[ct][j]);
    }
}

// ---------------- fused gather conv + self + bias + relu + pool ----------------
// 4 nodes per wave (16 lanes x 8 features each, dwordx4 gathers), 16 nodes per block.
// adj loaded cooperatively (1 VMEM / 16-edge window / group) and spread via __shfl.
__global__ __launch_bounds__(256) void k_conv(const unsigned short* __restrict__ h,
                                              const unsigned int* __restrict__ adj,
                                              const int* __restrict__ row_start,
                                              const int* __restrict__ deg,
                                              const float* __restrict__ dis,
                                              const float* __restrict__ bias,
                                              const int* __restrict__ batch,
                                              unsigned short* __restrict__ xout,
                                              float* __restrict__ gsum,
                                              float* __restrict__ gmax,
                                              float* __restrict__ cnt,
                                              int flags) {  // 1 = write xout, 2 = count
    __shared__ float lacc[16][128];
    __shared__ int lb[16];
    const int tid = threadIdx.x;
    const int wid = tid >> 6, lane = tid & 63;
    const int g = lane >> 4, l = lane & 15;
    const int nrow = wid * 4 + g;
    const int node = blockIdx.x * 16 + nrow;
    const int fb = l * 8;   // 8 features per lane

    const float di = dis[node];
    const float d2 = di * di;
    const uint4 hv = *(const uint4*)(h + (size_t)node * 128 + fb);
    const float4 bv0 = *(const float4*)(bias + fb);
    const float4 bv1 = *(const float4*)(bias + fb + 4);
    float acc[8];
    acc[0] = __uint_as_float(hv.x << 16)         * d2 + bv0.x;
    acc[1] = __uint_as_float(hv.x & 0xffff0000u) * d2 + bv0.y;
    acc[2] = __uint_as_float(hv.y << 16)         * d2 + bv0.z;
    acc[3] = __uint_as_float(hv.y & 0xffff0000u) * d2 + bv0.w;
    acc[4] = __uint_as_float(hv.z << 16)         * d2 + bv1.x;
    acc[5] = __uint_as_float(hv.z & 0xffff0000u) * d2 + bv1.y;
    acc[6] = __uint_as_float(hv.w << 16)         * d2 + bv1.z;
    acc[7] = __uint_as_float(hv.w & 0xffff0000u) * d2 + bv1.w;

    const int rs = row_start[node];
    const int n  = deg[node];           // uniform within 16-lane group
    const unsigned int* ap = adj + rs;
    const int sl = lane & 48;           // group base lane (g*16)

    for (int k = 0; k < n; k += 16) {
        unsigned int e = ap[min(k + l, n - 1)];   // cooperative adj load (tail clamped)
        #pragma unroll
        for (int j = 0; j < 16; ++j) {
            unsigned int ej = __shfl(e, sl + j);
            float w = (k + j < n) ? __uint_as_float(ej << 16) : 0.0f;
            const uint4 v = *(const uint4*)(h + (size_t)(ej >> 16) * 128 + fb);
            acc[0] = fmaf(__uint_as_float(v.x << 16),         w, acc[0]);
            acc[1] = fmaf(__uint_as_float(v.x & 0xffff0000u), w, acc[1]);
            acc[2] = fmaf(__uint_as_float(v.y << 16),         w, acc[2]);
            acc[3] = fmaf(__uint_as_float(v.y & 0xffff0000u), w, acc[3]);
            acc[4] = fmaf(__uint_as_float(v.z << 16),         w, acc[4]);
            acc[5] = fmaf(__uint_as_float(v.z & 0xffff0000u), w, acc[5]);
            acc[6] = fmaf(__uint_as_float(v.w << 16),         w, acc[6]);
            acc[7] = fmaf(__uint_as_float(v.w & 0xffff0000u), w, acc[7]);
        }
    }
    #pragma unroll
    for (int p = 0; p < 8; ++p) acc[p] = fmaxf(acc[p], 0.0f);

    if (flags & 1) {
        uint4 o;
        o.x = (unsigned)f2bf(acc[0]) | ((unsigned)f2bf(acc[1]) << 16);
        o.y = (unsigned)f2bf(acc[2]) | ((unsigned)f2bf(acc[3]) << 16);
        o.z = (unsigned)f2bf(acc[4]) | ((unsigned)f2bf(acc[5]) << 16);
        o.w = (unsigned)f2bf(acc[6]) | ((unsigned)f2bf(acc[7]) << 16);
        *(uint4*)(xout + (size_t)node * 128 + fb) = o;
    }

    // ---- block pool pre-reduction over 16 sorted nodes ----
    #pragma unroll
    for (int p = 0; p < 8; ++p) lacc[nrow][fb + p] = acc[p];
    if (l == 0) lb[nrow] = batch[node];
    __syncthreads();
    {
        const int f = tid & 127;
        const bool domax = tid >= 128;
        float s = lacc[0][f];
        int cur = lb[0], run = 1;
        #pragma unroll
        for (int w = 1; w < 16; ++w) {
            float a = lacc[w][f];
            if (lb[w] == cur) {
                s = domax ? fmaxf(s, a) : (s + a);
                ++run;
            } else {
                if (domax) {
                    atomicMax((int*)&gmax[cur * 128 + f], __float_as_int(s));
                } else {
                    atomicAdd(&gsum[cur * 128 + f], s);
                    if (f == 0 && (flags & 2)) atomicAdd(cnt + cur, (float)run);
                }
                s = a; cur = lb[w]; run = 1;
            }
        }
        if (domax) {
            atomicMax((int*)&gmax[cur * 128 + f], __float_as_int(s));
        } else {
            atomicAdd(&gsum[cur * 128 + f], s);
            if (f == 0 && (flags & 2)) atomicAdd(cnt + cur, (float)run);
        }
    }
}

// ---------------- final MLP: one block per graph ----------------
__global__ __launch_bounds__(256) void k_mlp(const float* __restrict__ gsum0,
                                             const float* __restrict__ gmax0,
                                             const float* __restrict__ gsum1,
                                             const float* __restrict__ gmax1,
                                             const float* __restrict__ cnt,
                                             const float* __restrict__ lW1,
                                             const float* __restrict__ lb1,
                                             const float* __restrict__ lW2,
                                             const float* __restrict__ lb2,
                                             float* __restrict__ out) {
    __shared__ float gl[512];
    __shared__ float hb[256];
    __shared__ float part[256];
    int r = blockIdx.x;
    float inv = 1.0f / fmaxf(cnt[r], 1.0f);
    for (int k = threadIdx.x; k < 512; k += 256) {
        int seg = k >> 7, f = k & 127;
        float v;
        if (seg == 0)      v = gsum0[r * 128 + f] * inv;
        else if (seg == 1) v = gmax0[r * 128 + f];
        else if (seg == 2) v = gsum1[r * 128 + f] * inv;
        else               v = gmax1[r * 128 + f];
        gl[k] = v;
    }
    __syncthreads();
    {
        int j = threadIdx.x;
        float acc = lb1[j];
        for (int k = 0; k < 512; ++k) acc += gl[k] * lW1[k * 256 + j];
        hb[j] = fmaxf(acc, 0.f);
    }
    __syncthreads();
    {
        int c = threadIdx.x & 15, ch = threadIdx.x >> 4;
        float p = 0.f;
        #pragma unroll
        for (int j2 = 0; j2 < 16; ++j2) p += hb[ch * 16 + j2] * lW2[(ch * 16 + j2) * 16 + c];
        part[threadIdx.x] = p;
    }
    __syncthreads();
    if (threadIdx.x < 16) {
        float s = lb2[threadIdx.x];
        #pragma unroll
        for (int ch2 = 0; ch2 < 16; ++ch2) s += part[ch2 * 16 + threadIdx.x];
        out[r * 16 + threadIdx.x] = s;
    }
}

extern "C" void kernel_launch(void* const* d_in, const int* in_sizes, int n_in,
                              void* d_out, int out_size, void* d_ws, size_t ws_size,
                              hipStream_t stream) {
    const float* x    = (const float*)d_in[0];
    const int*   ei   = (const int*)d_in[1];
    const int*   batch= (const int*)d_in[2];
    const float* W1   = (const float*)d_in[3];
    const float* b1   = (const float*)d_in[4];
    const float* W2   = (const float*)d_in[5];
    const float* b2   = (const float*)d_in[6];
    const float* lW1  = (const float*)d_in[7];
    const float* lb1  = (const float*)d_in[8];
    const float* lW2  = (const float*)d_in[9];
    const float* lb2  = (const float*)d_in[10];
    float* out = (float*)d_out;

    // ---- workspace layout ----
    unsigned short* hbuf = (unsigned short*)d_ws;          // NPAD*128 bf16 (h1, then h2)
    unsigned short* x0b  = hbuf + (size_t)NPAD * 128;      // NPAD*128 bf16 (x0)
    unsigned short* wf   = x0b + (size_t)NPAD * 128;       // 2*16384 bf16 frag-packed W1,W2
    float* dis   = (float*)(wf + 32768);                   // NPAD f32
    float* gsum0 = dis + NPAD;
    float* gmax0 = gsum0 + GG * HH;
    float* gsum1 = gmax0 + GG * HH;
    float* gmax1 = gsum1 + GG * HH;
    float* cnt   = gmax1 + GG * HH;                        // G
    int*   deg    = (int*)(cnt + GG);                      // NPAD
    int*   offs   = deg + NPAD;
    int*   cursor = offs + NPAD;
    int*   bsum   = cursor + NPAD;                         // 256
    unsigned int* adj = (unsigned int*)(bsum + 256);       // E packed + 256 pad

    // ---- CSR build ----
    hipMemsetAsync(deg, 0, NPAD * sizeof(int), stream);
    k_deg<<<(EE + 255) / 256, 256, 0, stream>>>(ei, deg);
    k_scan1<<<NBLK_SCAN, 256, 0, stream>>>(deg, offs, bsum, dis);
    k_scan2<<<1, 256, 0, stream>>>(bsum);
    k_scan3<<<NBLK_SCAN, 256, 0, stream>>>(offs, bsum, cursor);
    k_fill<<<(EE + 255) / 256, 256, 0, stream>>>(ei, dis, cursor, adj);

    // ---- W fragment packs + zero pools ----
    k_wfrag<<<2, 256, 0, stream>>>(W1, W2, wf);
    hipMemsetAsync(gsum0, 0, (size_t)(4 * GG * HH + GG) * sizeof(float), stream);

    // ---- conv1 ----
    k_gemm<<<GEMM_BLOCKS, 256, 0, stream>>>(x, (const unsigned short*)nullptr, wf, hbuf, 1);
    k_conv<<<NN / 16, 256, 0, stream>>>(hbuf, adj, offs, deg, dis, b1, batch,
                                        x0b, gsum0, gmax0, cnt, 3);
    // ---- conv2 ----
    k_gemm<<<GEMM_BLOCKS, 256, 0, stream>>>((const float*)nullptr, x0b, wf + 16384, hbuf, 0);
    k_conv<<<NN / 16, 256, 0, stream>>>(hbuf, adj, offs, deg, dis, b2, batch,
                                        x0b, gsum1, gmax1, cnt, 0);

    // ---- MLP head ----
    k_mlp<<<GG, 256, 0, stream>>>(gsum0, gmax0, gsum1, gmax1, cnt, lW1, lb1, lW2, lb2, out);
}